// Round 2
// baseline (347.362 us; speedup 1.0000x reference)
//
#include <hip/hip_runtime.h>
#include <hip/hip_bf16.h>

#define NSEG 512
#define EPSF 1e-6f
// d_ws layout: 4*NSEG doubles: [0..511]=count, [512..1023]=sum_x,
//              [1024..1535]=sum_log, [1536..2047]=sum_log2

__global__ __launch_bounds__(1024) void zero_ws_kernel(double* __restrict__ g) {
    int i = blockIdx.x * blockDim.x + threadIdx.x;
    if (i < 4 * NSEG) g[i] = 0.0;
}

__global__ __launch_bounds__(1024) void seg_stats_kernel(const float4* __restrict__ x4,
                                                         const int4* __restrict__ i4,
                                                         double* __restrict__ gacc,
                                                         int n4) {
    // [field][segment] layout: bank = seg % 32 -> full 32-bank spread
    __shared__ float acc[4 * NSEG];
    for (int i = threadIdx.x; i < 4 * NSEG; i += blockDim.x) acc[i] = 0.0f;
    __syncthreads();

    const int stride = gridDim.x * blockDim.x;
    for (int i = blockIdx.x * blockDim.x + threadIdx.x; i < n4; i += stride) {
        float4 xv = x4[i];
        int4 iv = i4[i];
        float vs[4] = {xv.x, xv.y, xv.z, xv.w};
        int ss[4] = {iv.x, iv.y, iv.z, iv.w};
#pragma unroll
        for (int c = 0; c < 4; ++c) {
            float v = vs[c];
            int s = ss[c];
            float lx = __logf(fabsf(v) + EPSF);
            // unsafeAtomicAdd -> native ds_add_f32 (no CAS loop, no return)
            unsafeAtomicAdd(&acc[s], 1.0f);                 // count
            unsafeAtomicAdd(&acc[NSEG + s], v);             // sum x
            unsafeAtomicAdd(&acc[2 * NSEG + s], lx);        // sum log
            unsafeAtomicAdd(&acc[3 * NSEG + s], lx * lx);   // sum log^2
        }
    }
    __syncthreads();

    // flush block partials to global f64 accumulators (HW f64 atomic)
    for (int i = threadIdx.x; i < 4 * NSEG; i += blockDim.x) {
        float v = acc[i];
        if (v != 0.0f) unsafeAtomicAdd(&gacc[i], (double)v);
    }
}

__global__ __launch_bounds__(512) void finalize_kernel(const double* __restrict__ gacc,
                                                       const float* __restrict__ tmean,
                                                       const float* __restrict__ tstd,
                                                       float* __restrict__ out) {
    int s = threadIdx.x;  // 512 threads, one per segment
    double cnt = gacc[s];
    double c = cnt > 1.0 ? cnt : 1.0;
    double mean_w = gacc[NSEG + s] / c;
    double mean_log = gacc[2 * NSEG + s] / c;
    double var = gacc[3 * NSEG + s] / c - mean_log * mean_log;
    if (var < 0.0) var = 0.0;
    double std_w = sqrt(var + 1e-6);
    double dm = mean_w - (double)tmean[s];
    double dsd = std_w - (double)tstd[s];
    double term = 0.5 * dm * dm + 0.5 * dsd * dsd;

    // wave64 reduce
#pragma unroll
    for (int off = 32; off > 0; off >>= 1) term += __shfl_down(term, off, 64);

    __shared__ double part[8];
    int wid = threadIdx.x >> 6;
    if ((threadIdx.x & 63) == 0) part[wid] = term;
    __syncthreads();
    if (threadIdx.x == 0) {
        double t = 0.0;
#pragma unroll
        for (int i = 0; i < 8; ++i) t += part[i];
        out[0] = (float)((t / (double)NSEG) * 0.01);
    }
}

extern "C" void kernel_launch(void* const* d_in, const int* in_sizes, int n_in,
                              void* d_out, int out_size, void* d_ws, size_t ws_size,
                              hipStream_t stream) {
    const float* x = (const float*)d_in[0];
    const int* idx = (const int*)d_in[1];
    const float* tmean = (const float*)d_in[2];
    const float* tstd = (const float*)d_in[3];
    float* out = (float*)d_out;
    double* gacc = (double*)d_ws;  // 4*NSEG doubles = 16 KiB

    int n = in_sizes[0];
    int n4 = n / 4;  // N_EDGES = 16777216, divisible by 4

    zero_ws_kernel<<<2, 1024, 0, stream>>>(gacc);
    seg_stats_kernel<<<512, 1024, 0, stream>>>((const float4*)x, (const int4*)idx, gacc, n4);
    finalize_kernel<<<1, 512, 0, stream>>>(gacc, tmean, tstd, out);
}

// Round 3
// 64.936 us; speedup vs baseline: 5.3493x; 5.3493x over previous
//
#include <hip/hip_runtime.h>
#include <hip/hip_bf16.h>

#define NSEG 512
#define EPSF 1e-6f
#define MAIN_GRID 1024
#define MAIN_BLOCK 256
#define WAVES_PER_BLOCK 4

// d_ws layout:
//   [0, 16KB)               : gacc f64[2048]  ([0..511]=count, [512..1023]=sum_x,
//                             [1024..1535]=sum_log, [1536..2047]=sum_log2)
//   [16KB, 16KB + 8MB)      : per-block f32 partials, entry layout e = s*4+f

__global__ __launch_bounds__(1024) void zero_ws_kernel(double* __restrict__ g) {
    int i = blockIdx.x * blockDim.x + threadIdx.x;
    if (i < 4 * NSEG) g[i] = 0.0;
}

__global__ __launch_bounds__(MAIN_BLOCK) void seg_stats_kernel(const float4* __restrict__ x4,
                                                               const int4* __restrict__ i4,
                                                               float* __restrict__ parts,
                                                               double* __restrict__ gacc,
                                                               int n4, int use_parts) {
    // Per-wave private histogram (no LDS atomics in the hot path).
    // hist[w][s*4+f]: 4 f32 fields per segment, 16B-aligned -> b128 RMW.
    __shared__ float hist[WAVES_PER_BLOCK][NSEG * 4];
    __shared__ unsigned tag[WAVES_PER_BLOCK][NSEG];

    const int wave = threadIdx.x >> 6;
    const int lane = threadIdx.x & 63;
    float* h = hist[wave];
    volatile unsigned* tg = tag[wave];  // volatile: force ds_write then ds_read (no forwarding)

    for (int i = threadIdx.x; i < WAVES_PER_BLOCK * NSEG * 4; i += MAIN_BLOCK)
        ((float*)hist)[i] = 0.0f;
    __syncthreads();

    const int stride = gridDim.x * blockDim.x;
    for (int i = blockIdx.x * blockDim.x + threadIdx.x; i < n4; i += stride) {
        float4 xv = x4[i];
        int4 iv = i4[i];
#pragma unroll
        for (int c = 0; c < 4; ++c) {
            float v = (c == 0) ? xv.x : (c == 1) ? xv.y : (c == 2) ? xv.z : xv.w;
            int s   = (c == 0) ? iv.x : (c == 1) ? iv.y : (c == 2) ? iv.z : iv.w;
            float lx = __logf(fabsf(v) + EPSF);
            float l2 = lx * lx;
            // Leader election: winner per distinct segment does a plain
            // (non-atomic) read-modify-write of all 4 fields in one b128 pair.
            // Losers (intra-wave duplicate segments, ~6% of lanes) retry.
            bool done = false;
            while (__ballot(!done)) {
                if (!done) {
                    tg[s] = (unsigned)lane;
                    unsigned w = tg[s];
                    if (w == (unsigned)lane) {
                        float4 hv = *(float4*)(h + (s << 2));
                        hv.x += 1.0f;
                        hv.y += v;
                        hv.z += lx;
                        hv.w += l2;
                        *(float4*)(h + (s << 2)) = hv;
                        done = true;
                    }
                }
            }
        }
    }
    __syncthreads();

    // Combine the 4 wave copies; flush per block.
    for (int e = threadIdx.x; e < NSEG * 4; e += MAIN_BLOCK) {
        float s0 = hist[0][e] + hist[1][e] + hist[2][e] + hist[3][e];
        if (use_parts) {
            parts[blockIdx.x * (NSEG * 4) + e] = s0;
        } else if (s0 != 0.0f) {
            unsafeAtomicAdd(&gacc[(e & 3) * NSEG + (e >> 2)], (double)s0);
        }
    }
}

#define RP_CHUNKS 16  // 1024 partial blocks / 64 per chunk
__global__ __launch_bounds__(256) void reduce_partials_kernel(const float* __restrict__ parts,
                                                              double* __restrict__ gacc) {
    // grid = 8 * RP_CHUNKS; low 3 bits of blockIdx pick the 256-entry group,
    // high bits pick the 64-row chunk of partial blocks.
    int eg = blockIdx.x & 7;
    int bc = blockIdx.x >> 3;
    int e = eg * 256 + threadIdx.x;  // 0..2047, entry layout s*4+f
    int b0 = bc * (MAIN_GRID / RP_CHUNKS);
    double acc = 0.0;
    for (int b = 0; b < MAIN_GRID / RP_CHUNKS; ++b)
        acc += (double)parts[(size_t)(b0 + b) * (NSEG * 4) + e];
    unsafeAtomicAdd(&gacc[(e & 3) * NSEG + (e >> 2)], acc);
}

__global__ __launch_bounds__(512) void finalize_kernel(const double* __restrict__ gacc,
                                                       const float* __restrict__ tmean,
                                                       const float* __restrict__ tstd,
                                                       float* __restrict__ out) {
    int s = threadIdx.x;  // 512 threads, one per segment
    double cnt = gacc[s];
    double c = cnt > 1.0 ? cnt : 1.0;
    double mean_w = gacc[NSEG + s] / c;
    double mean_log = gacc[2 * NSEG + s] / c;
    double var = gacc[3 * NSEG + s] / c - mean_log * mean_log;
    if (var < 0.0) var = 0.0;
    double std_w = sqrt(var + 1e-6);
    double dm = mean_w - (double)tmean[s];
    double dsd = std_w - (double)tstd[s];
    double term = 0.5 * dm * dm + 0.5 * dsd * dsd;

#pragma unroll
    for (int off = 32; off > 0; off >>= 1) term += __shfl_down(term, off, 64);

    __shared__ double part[8];
    int wid = threadIdx.x >> 6;
    if ((threadIdx.x & 63) == 0) part[wid] = term;
    __syncthreads();
    if (threadIdx.x == 0) {
        double t = 0.0;
#pragma unroll
        for (int i = 0; i < 8; ++i) t += part[i];
        out[0] = (float)((t / (double)NSEG) * 0.01);
    }
}

extern "C" void kernel_launch(void* const* d_in, const int* in_sizes, int n_in,
                              void* d_out, int out_size, void* d_ws, size_t ws_size,
                              hipStream_t stream) {
    const float* x = (const float*)d_in[0];
    const int* idx = (const int*)d_in[1];
    const float* tmean = (const float*)d_in[2];
    const float* tstd = (const float*)d_in[3];
    float* out = (float*)d_out;

    double* gacc = (double*)d_ws;
    float* parts = (float*)((char*)d_ws + 4 * NSEG * sizeof(double));
    size_t need = 4 * NSEG * sizeof(double) + (size_t)MAIN_GRID * NSEG * 4 * sizeof(float);
    int use_parts = (ws_size >= need) ? 1 : 0;

    int n = in_sizes[0];
    int n4 = n / 4;  // N_EDGES = 16777216, divisible by 4

    zero_ws_kernel<<<2, 1024, 0, stream>>>(gacc);
    seg_stats_kernel<<<MAIN_GRID, MAIN_BLOCK, 0, stream>>>((const float4*)x, (const int4*)idx,
                                                           parts, gacc, n4, use_parts);
    if (use_parts)
        reduce_partials_kernel<<<8 * RP_CHUNKS, 256, 0, stream>>>(parts, gacc);
    finalize_kernel<<<1, 512, 0, stream>>>(gacc, tmean, tstd, out);
}